// Round 3
// baseline (1425.009 us; speedup 1.0000x reference)
//
#include <hip/hip_runtime.h>
#include <stdint.h>

typedef unsigned short u16;
typedef __attribute__((ext_vector_type(8))) short short8v;
typedef __attribute__((ext_vector_type(4))) short short4v;
typedef __attribute__((ext_vector_type(4))) float f32x4;

#define B_ 8
#define T_ 8192
#define H_ 256
#define M_ 65536            // B_*T_
#define MH 16777216         // M_*H_
#define NCH 128             // chunks along T
#define CHL 64              // T_/NCH
#define NSEQ 16             // 2*B_
#define NS 2048             // NSEQ*NCH (lookback records per scan)

__device__ __forceinline__ u16 f2bf(float f) {
  union { float f; uint32_t u; } v; v.f = f;
  return (u16)((v.u + 0x7FFFu + ((v.u >> 16) & 1u)) >> 16);
}
__device__ __forceinline__ float bf2f(u16 s) {
  union { uint32_t u; float f; } v; v.u = ((uint32_t)s) << 16;
  return v.f;
}
__device__ __forceinline__ float sigm(float x) {
  return __fdividef(1.0f, 1.0f + __expf(-x));
}
__device__ __forceinline__ float tanhfast(float x) {
  return 1.0f - __fdividef(2.0f, __expf(2.0f * x) + 1.0f);
}

// ---------------- prep: cvt x -> bf16, cvt weights -> bf16, zero lookback flags ----------------
__global__ __launch_bounds__(256) void prep_kernel(
    const float* __restrict__ x, u16* __restrict__ xf,
    const float* __restrict__ w0, const float* __restrict__ w1, const float* __restrict__ w2,
    const float* __restrict__ w3, const float* __restrict__ w4, const float* __restrict__ w5,
    u16* __restrict__ wbf, int* __restrict__ flags) {
  const int bx = blockIdx.x;
  if (bx < 8192) {
    size_t i = ((size_t)bx * 256 + threadIdx.x) * 8;
    const float4* src = (const float4*)(x + i);
    float4 a = src[0], b = src[1];
    short8v o;
    o[0] = (short)f2bf(a.x); o[1] = (short)f2bf(a.y);
    o[2] = (short)f2bf(a.z); o[3] = (short)f2bf(a.w);
    o[4] = (short)f2bf(b.x); o[5] = (short)f2bf(b.y);
    o[6] = (short)f2bf(b.z); o[7] = (short)f2bf(b.w);
    *(short8v*)(xf + i) = o;
  } else if (bx < 8384) {
    const int r = bx - 8192;
    const int wsel = r >> 5, blk = r & 31;
    const float* s = (wsel == 0) ? w0 : (wsel == 1) ? w1 : (wsel == 2) ? w2
                   : (wsel == 3) ? w3 : (wsel == 4) ? w4 : w5;
    size_t i = ((size_t)blk * 256 + threadIdx.x) * 8;
    const float4* src = (const float4*)(s + i);
    float4 a = src[0], b = src[1];
    short8v o;
    o[0] = (short)f2bf(a.x); o[1] = (short)f2bf(a.y);
    o[2] = (short)f2bf(a.z); o[3] = (short)f2bf(a.w);
    o[4] = (short)f2bf(b.x); o[5] = (short)f2bf(b.y);
    o[6] = (short)f2bf(b.z); o[7] = (short)f2bf(b.w);
    *(short8v*)(wbf + (size_t)wsel * 65536 + i) = o;
  } else {
    // zero 2*NS flags (both scans)
    int4* f4 = (int4*)flags;
#pragma unroll
    for (int k = 0; k < 4; ++k) f4[k * 256 + threadIdx.x] = (int4){0, 0, 0, 0};
  }
}

// ---------------- GEMM: C[m,n] = epi(sum_k A[m,k]*Bw[n,k]) ----------------
// A: M x 256 bf16 row-major; Bw: 256x256 bf16 (N,K); C: M x 256 bf16.
// blockIdx.z selects direction: A += z*strideA, Bw += z*196608, C/addm += z*MH.
// EPI: 0 = tanh(+bias), 1 = +bias, 3 = +addm (in-place OK).
// REVZ: if set, z==1 reads A rows time-reversed per batch.
__device__ __forceinline__ void g2l16(const void* g, void* l) {
  __builtin_amdgcn_global_load_lds((const __attribute__((address_space(1))) void*)g,
                                   (__attribute__((address_space(3))) void*)l, 16, 0, 0);
}

template <int EPI, int REVZ>
__global__ __launch_bounds__(256) void gemm_k(const u16* __restrict__ A, size_t strideA,
                                              const u16* __restrict__ Bw,
                                              const float* __restrict__ bias0,
                                              const float* __restrict__ bias1,
                                              const u16* addm, u16* C) {
  __shared__ __align__(16) char lds[32768];
  char* ldsA = lds;
  char* ldsB = lds + 16384;
  const int bz = blockIdx.z;
  A += (size_t)bz * strideA;
  Bw += (size_t)bz * 196608;
  C += (size_t)bz * (size_t)MH;
  if (EPI == 3) addm += (size_t)bz * (size_t)MH;
  const float* bias = bz ? bias1 : bias0;

  const int tid = threadIdx.x;
  const int l = tid & 63, w = tid >> 6;
  const int tm = blockIdx.x, tn = blockIdx.y;
  const int m0 = (w >> 1) * 64, n0 = (w & 1) * 64;
  const int wbase = w * 1024;
  const bool rev = REVZ && (bz == 1);

  f32x4 vzero = {0.f, 0.f, 0.f, 0.f};
  f32x4 acc[4][4];
#pragma unroll
  for (int i = 0; i < 4; ++i)
#pragma unroll
    for (int j = 0; j < 4; ++j) acc[i][j] = vzero;

#pragma unroll
  for (int k0 = 0; k0 < 256; k0 += 64) {
#pragma unroll
    for (int is = 0; is < 4; ++is) {
      const int o = is * 4096 + tid * 16;
      const int row = o >> 7;                   // 0..127
      const int cb = o & 127;                   // byte within 128B row
      int rA = tm * 128 + row;
      if (rev) { int bb = rA >> 13; int t = rA & 8191; rA = (bb << 13) + (8191 - t); }
      const char* gA = (const char*)A + (size_t)rA * 512 + k0 * 2 + cb;
      g2l16(gA, ldsA + is * 4096 + wbase);
      const int rB = tn * 128 + row;
      const char* gB = (const char*)Bw + (size_t)rB * 512 + k0 * 2 + cb;
      g2l16(gB, ldsB + is * 4096 + wbase);
    }
    __syncthreads();                            // drains vmcnt (global_load_lds) + barrier
#pragma unroll
    for (int ks = 0; ks < 2; ++ks) {
      short8v av[4], bv[4];
#pragma unroll
      for (int i = 0; i < 4; ++i) {
        av[i] = *(const short8v*)(ldsA + (m0 + i * 16 + (l & 15)) * 128 + ks * 64 + (l >> 4) * 16);
        bv[i] = *(const short8v*)(ldsB + (n0 + i * 16 + (l & 15)) * 128 + ks * 64 + (l >> 4) * 16);
      }
#pragma unroll
      for (int i = 0; i < 4; ++i)
#pragma unroll
        for (int j = 0; j < 4; ++j)
          acc[i][j] = __builtin_amdgcn_mfma_f32_16x16x32_bf16(av[i], bv[j], acc[i][j], 0, 0, 0);
    }
    __syncthreads();                            // protect LDS before next stage
  }

  // epilogue: D col = lane&15, row = (lane>>4)*4 + r  -> stage bf16 tile in LDS,
  // then coalesced short8 stores.
  u16* lt = (u16*)lds;
  const int colL = n0 + (l & 15);
  const int rowL0 = m0 + ((l >> 4) << 2);
#pragma unroll
  for (int j = 0; j < 4; ++j) {
    const int cl = colL + j * 16;
    const int cg = tn * 128 + cl;
    const float bv = (EPI == 3) ? 0.f : bias[cg];
#pragma unroll
    for (int i = 0; i < 4; ++i)
#pragma unroll
      for (int r = 0; r < 4; ++r) {
        const int rl = rowL0 + i * 16 + r;
        float xv = acc[i][j][r] + bv;
        if (EPI == 3) xv += bf2f(addm[(size_t)(tm * 128 + rl) * 256 + cg]);
        if (EPI == 0) xv = tanhfast(xv);
        lt[rl * 128 + cl] = f2bf(xv);
      }
  }
  __syncthreads();
#pragma unroll
  for (int itr = 0; itr < 8; ++itr) {
    const int rl = w * 32 + itr * 4 + (l >> 4);
    const int cb = (l & 15) * 16;               // byte offset in 256B tile row
    short8v v = *(const short8v*)((const char*)lt + rl * 256 + cb);
    *(short8v*)((char*)C + (size_t)(tm * 128 + rl) * 512 + tn * 256 + cb) = v;
  }
}

// ---------------- single-pass chunked scan with decoupled lookback ----------------
// h_t = A_t h_{t-1} + b_t per (d,b,h) channel along T. One wave per (seq=d*8+b, chunk c).
// lane owns 4 channels. Publishes local (P,q) -> flag 1; inclusive q (=h at chunk end,
// since h_init=0) -> flag 2. Lookback walks predecessors in batches of 8 flags.
__device__ __forceinline__ void compute_Ab(float zf, float ag, float hp, float dr,
                                           float& Aa, float& bb) {
  const float u = sigm(ag);
  const float g = u * (1.f - u) * dr;
  Aa = u + (hp - zf) * g;
  bb = u * hp + (1.f - u) * zf - Aa * hp;
}

template <int ITER>
__global__ __launch_bounds__(256) void scan_kernel(
    const u16* __restrict__ zb, const u16* __restrict__ zub,
    const u16* __restrict__ s1b,
    const float* __restrict__ Wf_rec, const float* __restrict__ Wb_rec,
    float* __restrict__ pubP, float* __restrict__ pubq,
    float* __restrict__ inclq, int* __restrict__ flags,
    u16* __restrict__ s1out, float* __restrict__ out, float* __restrict__ hn) {
  const int wid = blockIdx.x * 4 + (threadIdx.x >> 6);   // == seq*NCH + c
  const int lane = threadIdx.x & 63;
  const int c = wid & (NCH - 1);
  const int seq = wid >> 7;
  const int b = seq & 7;
  const int d = seq >> 3;
  const int h0 = lane * 4;
  const float* Wr = d ? Wb_rec : Wf_rec;
  float dr[4];
#pragma unroll
  for (int j = 0; j < 4; ++j) dr[j] = Wr[(h0 + j) * 257];
  const size_t off = (size_t)d * MH + ((size_t)b * T_ + (size_t)c * CHL) * H_ + h0;
  const u16* zp = zb + off;
  const u16* zup = zub + off;
  const u16* s1p = s1b + off;

  // ---- local pass ----
  float Pv[4] = {1.f, 1.f, 1.f, 1.f}, qv[4] = {0.f, 0.f, 0.f, 0.f};
#pragma unroll 4
  for (int it = 0; it < CHL; ++it) {
    const size_t ix = (size_t)it * H_;
    short4v z4 = *(const short4v*)(zp + ix);
    short4v a4 = *(const short4v*)(zup + ix);
    short4v s4 = {0, 0, 0, 0};
    if (ITER == 2) s4 = *(const short4v*)(s1p + ix);
#pragma unroll
    for (int j = 0; j < 4; ++j) {
      const float zf = bf2f((u16)z4[j]);
      const float ag = bf2f((u16)a4[j]);
      const float hp = (ITER == 2) ? bf2f((u16)s4[j]) : 0.f;
      float Aa, bb;
      compute_Ab(zf, ag, hp, dr[j], Aa, bb);
      qv[j] = Aa * qv[j] + bb;
      Pv[j] *= Aa;
    }
  }

  const size_t ps = (size_t)wid * 256 + h0;
  if (c > 0) {
    *(f32x4*)(pubP + ps) = (f32x4){Pv[0], Pv[1], Pv[2], Pv[3]};
    *(f32x4*)(pubq + ps) = (f32x4){qv[0], qv[1], qv[2], qv[3]};
    if (lane == 0)
      __hip_atomic_store(&flags[wid], 1, __ATOMIC_RELEASE, __HIP_MEMORY_SCOPE_AGENT);
  }

  // ---- lookback ----
  float hs[4] = {0.f, 0.f, 0.f, 0.f};
  if (c > 0) {
    float Pb[4] = {1.f, 1.f, 1.f, 1.f}, qb[4] = {0.f, 0.f, 0.f, 0.f};
    const int fb = seq * NCH;
    int j = c - 1;
    bool done = false;
    while (!done) {
      const int nb = (j + 1 < 8) ? (j + 1) : 8;
      int f[8];
      while (true) {
        bool ok = true;
        for (int k = 0; k < nb; ++k) {
          f[k] = __hip_atomic_load(&flags[fb + j - k], __ATOMIC_ACQUIRE, __HIP_MEMORY_SCOPE_AGENT);
          ok &= (f[k] != 0);
        }
        if (ok) break;
        __builtin_amdgcn_s_sleep(2);
      }
      for (int k = 0; k < nb && !done; ++k) {
        const size_t js = (size_t)(fb + j - k) * 256 + h0;
        if (f[k] == 2) {
          f32x4 iq = *(const f32x4*)(inclq + js);
#pragma unroll
          for (int jj = 0; jj < 4; ++jj) hs[jj] = Pb[jj] * iq[jj] + qb[jj];
          done = true;
        } else {
          f32x4 Pj = *(const f32x4*)(pubP + js);
          f32x4 qj = *(const f32x4*)(pubq + js);
#pragma unroll
          for (int jj = 0; jj < 4; ++jj) {
            qb[jj] = Pb[jj] * qj[jj] + qb[jj];
            Pb[jj] *= Pj[jj];
          }
        }
      }
      j -= nb;
    }
  }

  // ---- publish inclusive (h at end of this chunk; h_init = 0 so only q matters) ----
  if (c < NCH - 1) {
    f32x4 hi;
#pragma unroll
    for (int jj = 0; jj < 4; ++jj) hi[jj] = Pv[jj] * hs[jj] + qv[jj];
    *(f32x4*)(inclq + ps) = hi;
    if (lane == 0)
      __hip_atomic_store(&flags[wid], 2, __ATOMIC_RELEASE, __HIP_MEMORY_SCOPE_AGENT);
  }

  // ---- replay, emit states ----
  float hc[4] = {hs[0], hs[1], hs[2], hs[3]};
  if (ITER == 1 && c == 0) {
    // s1 holds states1 shifted by +1 row; row t=0 is h_{-1} = 0
    *(short4v*)(s1out + off) = (short4v){0, 0, 0, 0};
  }
#pragma unroll 4
  for (int it = 0; it < CHL; ++it) {
    const size_t ix = (size_t)it * H_;
    short4v z4 = *(const short4v*)(zp + ix);
    short4v a4 = *(const short4v*)(zup + ix);
    short4v s4 = {0, 0, 0, 0};
    if (ITER == 2) s4 = *(const short4v*)(s1p + ix);
#pragma unroll
    for (int j = 0; j < 4; ++j) {
      const float zf = bf2f((u16)z4[j]);
      const float ag = bf2f((u16)a4[j]);
      const float hp = (ITER == 2) ? bf2f((u16)s4[j]) : 0.f;
      float Aa, bb;
      compute_Ab(zf, ag, hp, dr[j], Aa, bb);
      hc[j] = Aa * hc[j] + bb;
    }
    const int t = c * CHL + it;
    if (ITER == 1) {
      if (t < T_ - 1) {
        short4v o = {(short)f2bf(hc[0]), (short)f2bf(hc[1]),
                     (short)f2bf(hc[2]), (short)f2bf(hc[3])};
        *(short4v*)(s1out + off + ix + H_) = o;   // row t+1
      }
    } else {
      const size_t to = (d == 0) ? ((size_t)b * T_ + t) * 512 + h0
                                 : ((size_t)b * T_ + (T_ - 1 - t)) * 512 + 256 + h0;
      *(f32x4*)(out + to) = (f32x4){hc[0], hc[1], hc[2], hc[3]};
      if (t == T_ - 1)
        *(f32x4*)(hn + (size_t)(d * 8 + b) * 256 + h0) = (f32x4){hc[0], hc[1], hc[2], hc[3]};
    }
  }
}

// ---------------- host ----------------
extern "C" void kernel_launch(void* const* d_in, const int* in_sizes, int n_in,
                              void* d_out, int out_size, void* d_ws, size_t ws_size,
                              hipStream_t stream) {
  const float* x      = (const float*)d_in[0];
  const float* Wf_in  = (const float*)d_in[1];
  const float* bf_in  = (const float*)d_in[2];
  const float* Wf_rec = (const float*)d_in[3];
  const float* Uf_z   = (const float*)d_in[4];
  const float* bf_u   = (const float*)d_in[5];
  const float* Wb_in  = (const float*)d_in[6];
  const float* bb_in  = (const float*)d_in[7];
  const float* Wb_rec = (const float*)d_in[8];
  const float* Ub_z   = (const float*)d_in[9];
  const float* bb_u   = (const float*)d_in[10];

  char* ws = (char*)d_ws;
  const size_t BF = 33554432;                   // bytes of one bf16 [M_ x H_] buffer
  u16* xf  = (u16*)(ws + 0 * BF);               // x as bf16
  u16* z0  = (u16*)(ws + 1 * BF);               // z, dirs contiguous [2][M][H]
  u16* zu0 = (u16*)(ws + 3 * BF);               // zu, then zuh = zu + s1*W (in-place)
  u16* s10 = (u16*)(ws + 5 * BF);               // states1 shifted (+1 row), dirs contiguous
  u16* wbf = (u16*)(ws + 7 * BF);               // 6 x 256x256 bf16 weights (786432 B)
  char* pb = ws + 7 * BF + 1048576;
  float* pubP1  = (float*)(pb);                 // NS*256 f32 = 2 MB each
  float* pubq1  = (float*)(pb + 2097152);
  float* inclq1 = (float*)(pb + 2 * 2097152);
  float* pubP2  = (float*)(pb + 3 * 2097152);
  float* pubq2  = (float*)(pb + 4 * 2097152);
  float* inclq2 = (float*)(pb + 5 * 2097152);
  int*   flags  = (int*)(pb + 6 * 2097152);     // 2*NS ints (scan1 then scan2)
  int*   flags2 = flags + NS;
  (void)ws_size; (void)in_sizes; (void)n_in; (void)out_size;

  float* outp = (float*)d_out;                  // (B,T,512)
  float* hnp  = outp + (size_t)33554432;        // (2,B,256)

  dim3 gg(512, 2, 2);

  prep_kernel<<<8385, 256, 0, stream>>>(x, xf, Wf_in, Uf_z, Wf_rec, Wb_in, Ub_z, Wb_rec,
                                        wbf, flags);

  // z = tanh(x W_in^T + b_in); z==1 reads x time-reversed per batch
  gemm_k<0, 1><<<gg, 256, 0, stream>>>(xf, 0, wbf + 0 * 65536, bf_in, bb_in, nullptr, z0);
  // zu = z U_z^T + b_u
  gemm_k<1, 0><<<gg, 256, 0, stream>>>(z0, MH, wbf + 1 * 65536, bf_u, bb_u, nullptr, zu0);

  // DEER iteration 1 (h_prev = 0): single-pass scan -> s1 (shifted states)
  scan_kernel<1><<<512, 256, 0, stream>>>(z0, zu0, s10, Wf_rec, Wb_rec,
                                          pubP1, pubq1, inclq1, flags,
                                          s10, nullptr, nullptr);

  // zuh = zu + states1_shifted W_rec^T  (in-place into zu)
  gemm_k<3, 0><<<gg, 256, 0, stream>>>(s10, MH, wbf + 2 * 65536, nullptr, nullptr, zu0, zu0);

  // DEER iteration 2: single-pass scan -> output + h_n
  scan_kernel<2><<<512, 256, 0, stream>>>(z0, zu0, s10, Wf_rec, Wb_rec,
                                          pubP2, pubq2, inclq2, flags2,
                                          nullptr, outp, hnp);
}

// Round 4
// 372.798 us; speedup vs baseline: 3.8225x; 3.8225x over previous
//
#include <hip/hip_runtime.h>
#include <stdint.h>

typedef unsigned short u16;
typedef __attribute__((ext_vector_type(8))) short short8v;
typedef __attribute__((ext_vector_type(4))) short short4v;
typedef __attribute__((ext_vector_type(4))) float f32x4;

#define B_ 8
#define T_ 8192
#define H_ 256
#define M_ 65536            // B_*T_
#define MH 16777216         // M_*H_
#define NCH 256             // chunks along T
#define CHL 32              // T_/NCH
#define NCHAN 4096          // 2*B_*H_

__device__ __forceinline__ u16 f2bf(float f) {
  union { float f; uint32_t u; } v; v.f = f;
  return (u16)((v.u + 0x7FFFu + ((v.u >> 16) & 1u)) >> 16);
}
__device__ __forceinline__ float bf2f(u16 s) {
  union { uint32_t u; float f; } v; v.u = ((uint32_t)s) << 16;
  return v.f;
}
__device__ __forceinline__ float sigm(float x) {
  return __fdividef(1.0f, 1.0f + __expf(-x));
}
__device__ __forceinline__ float tanhfast(float x) {
  return 1.0f - __fdividef(2.0f, __expf(2.0f * x) + 1.0f);
}

// ---------------- prep: cvt x -> bf16, cvt weights -> bf16 ----------------
__global__ __launch_bounds__(256) void prep_kernel(
    const float* __restrict__ x, u16* __restrict__ xf,
    const float* __restrict__ w0, const float* __restrict__ w1, const float* __restrict__ w2,
    const float* __restrict__ w3, const float* __restrict__ w4, const float* __restrict__ w5,
    u16* __restrict__ wbf) {
  const int bx = blockIdx.x;
  const float* src;
  u16* dst;
  size_t i;
  if (bx < 8192) {
    i = ((size_t)bx * 256 + threadIdx.x) * 8;
    src = x; dst = xf;
  } else {
    const int r = bx - 8192;
    const int wsel = r >> 5, blk = r & 31;
    src = (wsel == 0) ? w0 : (wsel == 1) ? w1 : (wsel == 2) ? w2
        : (wsel == 3) ? w3 : (wsel == 4) ? w4 : w5;
    dst = wbf + (size_t)wsel * 65536;
    i = ((size_t)blk * 256 + threadIdx.x) * 8;
  }
  const float4* s4 = (const float4*)(src + i);
  float4 a = s4[0], b = s4[1];
  short8v o;
  o[0] = (short)f2bf(a.x); o[1] = (short)f2bf(a.y);
  o[2] = (short)f2bf(a.z); o[3] = (short)f2bf(a.w);
  o[4] = (short)f2bf(b.x); o[5] = (short)f2bf(b.y);
  o[6] = (short)f2bf(b.z); o[7] = (short)f2bf(b.w);
  *(short8v*)(dst + i) = o;
}

// ---------------- GEMM: C[m,n] = epi(sum_k A[m,k]*Bw[n,k]) ----------------
// A: M x 256 bf16 row-major; Bw: 256x256 bf16 (N,K); C: M x 256 bf16.
// blockIdx.z selects direction: A += z*strideA, Bw += z*196608, C/addm += z*MH.
// EPI: 0 = tanh(+bias), 1 = +bias, 3 = +addm (in-place OK).
// REVZ: if set, z==1 reads A rows time-reversed per batch.
__device__ __forceinline__ void g2l16(const void* g, void* l) {
  __builtin_amdgcn_global_load_lds((const __attribute__((address_space(1))) void*)g,
                                   (__attribute__((address_space(3))) void*)l, 16, 0, 0);
}

template <int EPI, int REVZ>
__global__ __launch_bounds__(256) void gemm_k(const u16* __restrict__ A, size_t strideA,
                                              const u16* __restrict__ Bw,
                                              const float* __restrict__ bias0,
                                              const float* __restrict__ bias1,
                                              const u16* addm, u16* C) {
  __shared__ __align__(16) char lds[32768];
  char* ldsA = lds;
  char* ldsB = lds + 16384;
  const int bz = blockIdx.z;
  A += (size_t)bz * strideA;
  Bw += (size_t)bz * 196608;
  C += (size_t)bz * (size_t)MH;
  if (EPI == 3) addm += (size_t)bz * (size_t)MH;
  const float* bias = bz ? bias1 : bias0;

  const int tid = threadIdx.x;
  const int l = tid & 63, w = tid >> 6;
  const int tm = blockIdx.x, tn = blockIdx.y;
  const int m0 = (w >> 1) * 64, n0 = (w & 1) * 64;
  const int wbase = w * 1024;
  const bool rev = REVZ && (bz == 1);

  f32x4 vzero = {0.f, 0.f, 0.f, 0.f};
  f32x4 acc[4][4];
#pragma unroll
  for (int i = 0; i < 4; ++i)
#pragma unroll
    for (int j = 0; j < 4; ++j) acc[i][j] = vzero;

#pragma unroll
  for (int k0 = 0; k0 < 256; k0 += 64) {
#pragma unroll
    for (int is = 0; is < 4; ++is) {
      const int o = is * 4096 + tid * 16;
      const int row = o >> 7;                   // 0..127
      const int cb = o & 127;                   // byte within 128B row
      int rA = tm * 128 + row;
      if (rev) { int bb = rA >> 13; int t = rA & 8191; rA = (bb << 13) + (8191 - t); }
      const char* gA = (const char*)A + (size_t)rA * 512 + k0 * 2 + cb;
      g2l16(gA, ldsA + is * 4096 + wbase);
      const int rB = tn * 128 + row;
      const char* gB = (const char*)Bw + (size_t)rB * 512 + k0 * 2 + cb;
      g2l16(gB, ldsB + is * 4096 + wbase);
    }
    __syncthreads();                            // drains vmcnt (global_load_lds) + barrier
#pragma unroll
    for (int ks = 0; ks < 2; ++ks) {
      short8v av[4], bv[4];
#pragma unroll
      for (int i = 0; i < 4; ++i) {
        av[i] = *(const short8v*)(ldsA + (m0 + i * 16 + (l & 15)) * 128 + ks * 64 + (l >> 4) * 16);
        bv[i] = *(const short8v*)(ldsB + (n0 + i * 16 + (l & 15)) * 128 + ks * 64 + (l >> 4) * 16);
      }
#pragma unroll
      for (int i = 0; i < 4; ++i)
#pragma unroll
        for (int j = 0; j < 4; ++j)
          acc[i][j] = __builtin_amdgcn_mfma_f32_16x16x32_bf16(av[i], bv[j], acc[i][j], 0, 0, 0);
    }
    __syncthreads();                            // protect LDS before next stage
  }

  // epilogue: D col = lane&15, row = (lane>>4)*4 + r  -> stage bf16 tile in LDS,
  // then coalesced short8 stores.
  u16* lt = (u16*)lds;
  const int colL = n0 + (l & 15);
  const int rowL0 = m0 + ((l >> 4) << 2);
#pragma unroll
  for (int j = 0; j < 4; ++j) {
    const int cl = colL + j * 16;
    const int cg = tn * 128 + cl;
    const float bv = (EPI == 3) ? 0.f : bias[cg];
#pragma unroll
    for (int i = 0; i < 4; ++i)
#pragma unroll
      for (int r = 0; r < 4; ++r) {
        const int rl = rowL0 + i * 16 + r;
        float xv = acc[i][j][r] + bv;
        if (EPI == 3) xv += bf2f(addm[(size_t)(tm * 128 + rl) * 256 + cg]);
        if (EPI == 0) xv = tanhfast(xv);
        lt[rl * 128 + cl] = f2bf(xv);
      }
  }
  __syncthreads();
#pragma unroll
  for (int itr = 0; itr < 8; ++itr) {
    const int rl = w * 32 + itr * 4 + (l >> 4);
    const int cb = (l & 15) * 16;               // byte offset in 256B tile row
    short8v v = *(const short8v*)((const char*)lt + rl * 256 + cb);
    *(short8v*)((char*)C + (size_t)(tm * 128 + rl) * 512 + tn * 256 + cb) = v;
  }
}

// ---------------- scan: h_t = A_t h_{t-1} + b_t (3-pass chunked) ----------------
// lane owns 4 h-channels (short4 loads); wave covers all 256 h of one (d,b,chunk).
// A_t at t=0 need not be zeroed: h_{-1}=0 makes its value irrelevant in P/q/h.
__device__ __forceinline__ void compute_Ab(float zf, float ag, float hp, float dr,
                                           float& Aa, float& bb) {
  const float u = sigm(ag);
  const float g = u * (1.f - u) * dr;
  Aa = u + (hp - zf) * g;
  bb = u * hp + (1.f - u) * zf - Aa * hp;
}

// pass 1: per-chunk (P = prod A, q = affine-combined b)
template <int ITER>
__global__ __launch_bounds__(256) void scan_p1_kernel(
    const u16* __restrict__ zb, const u16* __restrict__ zub,
    const u16* __restrict__ s1b,
    const float* __restrict__ Wf_rec, const float* __restrict__ Wb_rec,
    float* __restrict__ P, float* __restrict__ q) {
  const int wid = blockIdx.x * 4 + (threadIdx.x >> 6);
  const int lane = threadIdx.x & 63;
  const int c = wid & (NCH - 1);
  const int tmp = wid >> 8;
  const int b = tmp & 7;
  const int d = tmp >> 3;
  const int h0 = lane * 4;
  const float* Wr = d ? Wb_rec : Wf_rec;
  float dr[4];
#pragma unroll
  for (int j = 0; j < 4; ++j) dr[j] = Wr[(h0 + j) * 257];
  const size_t off = (size_t)d * MH + ((size_t)b * T_ + (size_t)c * CHL) * H_ + h0;
  const u16* zp = zb + off;
  const u16* zup = zub + off;
  const u16* s1p = s1b + off;
  float Pv[4] = {1.f, 1.f, 1.f, 1.f}, qv[4] = {0.f, 0.f, 0.f, 0.f};
#pragma unroll 4
  for (int it = 0; it < CHL; ++it) {
    const size_t ix = (size_t)it * H_;
    short4v z4 = *(const short4v*)(zp + ix);
    short4v a4 = *(const short4v*)(zup + ix);
    short4v s4 = {0, 0, 0, 0};
    if (ITER == 2) s4 = *(const short4v*)(s1p + ix);
#pragma unroll
    for (int j = 0; j < 4; ++j) {
      const float zf = bf2f((u16)z4[j]);
      const float ag = bf2f((u16)a4[j]);
      const float hp = (ITER == 2) ? bf2f((u16)s4[j]) : 0.f;
      float Aa, bb;
      compute_Ab(zf, ag, hp, dr[j], Aa, bb);
      qv[j] = Aa * qv[j] + bb;
      Pv[j] *= Aa;
    }
  }
  const int ch0 = (d * 8 + b) * 256 + h0;
  *(f32x4*)(P + (size_t)c * NCHAN + ch0) = (f32x4){Pv[0], Pv[1], Pv[2], Pv[3]};
  *(f32x4*)(q + (size_t)c * NCHAN + ch0) = (f32x4){qv[0], qv[1], qv[2], qv[3]};
}

// pass 2: exclusive scan over chunk summaries per channel
__global__ __launch_bounds__(256) void scan_p2_kernel(const float* __restrict__ P,
                                                      const float* __restrict__ q,
                                                      float* __restrict__ hstart) {
  const int ch = blockIdx.x * 256 + threadIdx.x;    // 0..4095
  float hs = 0.f;
#pragma unroll 8
  for (int c = 0; c < NCH; ++c) {
    hstart[c * NCHAN + ch] = hs;
    hs = P[c * NCHAN + ch] * hs + q[c * NCHAN + ch];
  }
}

// pass 3: replay chunk with known h_start, emit states
template <int ITER>
__global__ __launch_bounds__(256) void scan_p3_kernel(
    const u16* __restrict__ zb, const u16* __restrict__ zub,
    const u16* __restrict__ s1b,
    const float* __restrict__ Wf_rec, const float* __restrict__ Wb_rec,
    const float* __restrict__ hstart,
    u16* __restrict__ s1out, float* __restrict__ out, float* __restrict__ hn) {
  const int wid = blockIdx.x * 4 + (threadIdx.x >> 6);
  const int lane = threadIdx.x & 63;
  const int c = wid & (NCH - 1);
  const int tmp = wid >> 8;
  const int b = tmp & 7;
  const int d = tmp >> 3;
  const int h0 = lane * 4;
  const float* Wr = d ? Wb_rec : Wf_rec;
  float dr[4];
#pragma unroll
  for (int j = 0; j < 4; ++j) dr[j] = Wr[(h0 + j) * 257];
  const size_t off = (size_t)d * MH + ((size_t)b * T_ + (size_t)c * CHL) * H_ + h0;
  const u16* zp = zb + off;
  const u16* zup = zub + off;
  const u16* s1p = s1b + off;
  const int ch0 = (d * 8 + b) * 256 + h0;
  f32x4 h4 = *(const f32x4*)(hstart + (size_t)c * NCHAN + ch0);
  float hc[4] = {h4[0], h4[1], h4[2], h4[3]};
  if (ITER == 1 && c == 0) {
    // s1 holds states1 shifted by +1 row; row t=0 is h_{-1} = 0
    *(short4v*)(s1out + off) = (short4v){0, 0, 0, 0};
  }
#pragma unroll 4
  for (int it = 0; it < CHL; ++it) {
    const size_t ix = (size_t)it * H_;
    short4v z4 = *(const short4v*)(zp + ix);
    short4v a4 = *(const short4v*)(zup + ix);
    short4v s4 = {0, 0, 0, 0};
    if (ITER == 2) s4 = *(const short4v*)(s1p + ix);
#pragma unroll
    for (int j = 0; j < 4; ++j) {
      const float zf = bf2f((u16)z4[j]);
      const float ag = bf2f((u16)a4[j]);
      const float hp = (ITER == 2) ? bf2f((u16)s4[j]) : 0.f;
      float Aa, bb;
      compute_Ab(zf, ag, hp, dr[j], Aa, bb);
      hc[j] = Aa * hc[j] + bb;
    }
    const int t = c * CHL + it;
    if (ITER == 1) {
      if (t < T_ - 1) {
        short4v o = {(short)f2bf(hc[0]), (short)f2bf(hc[1]),
                     (short)f2bf(hc[2]), (short)f2bf(hc[3])};
        *(short4v*)(s1out + off + ix + H_) = o;   // row t+1
      }
    } else {
      const size_t to = (d == 0) ? ((size_t)b * T_ + t) * 512 + h0
                                 : ((size_t)b * T_ + (T_ - 1 - t)) * 512 + 256 + h0;
      *(f32x4*)(out + to) = (f32x4){hc[0], hc[1], hc[2], hc[3]};
      if (t == T_ - 1)
        *(f32x4*)(hn + (size_t)(d * 8 + b) * 256 + h0) = (f32x4){hc[0], hc[1], hc[2], hc[3]};
    }
  }
}

// ---------------- host ----------------
extern "C" void kernel_launch(void* const* d_in, const int* in_sizes, int n_in,
                              void* d_out, int out_size, void* d_ws, size_t ws_size,
                              hipStream_t stream) {
  const float* x      = (const float*)d_in[0];
  const float* Wf_in  = (const float*)d_in[1];
  const float* bf_in  = (const float*)d_in[2];
  const float* Wf_rec = (const float*)d_in[3];
  const float* Uf_z   = (const float*)d_in[4];
  const float* bf_u   = (const float*)d_in[5];
  const float* Wb_in  = (const float*)d_in[6];
  const float* bb_in  = (const float*)d_in[7];
  const float* Wb_rec = (const float*)d_in[8];
  const float* Ub_z   = (const float*)d_in[9];
  const float* bb_u   = (const float*)d_in[10];

  char* ws = (char*)d_ws;
  const size_t BF = 33554432;                   // bytes of one bf16 [M_ x H_] buffer
  u16* xf  = (u16*)(ws + 0 * BF);               // x as bf16
  u16* z0  = (u16*)(ws + 1 * BF);               // z, dirs contiguous [2][M][H]
  u16* zu0 = (u16*)(ws + 3 * BF);               // zu, then zuh = zu + s1*W (in-place)
  u16* s10 = (u16*)(ws + 5 * BF);               // states1 shifted (+1 row), dirs contiguous
  u16* wbf = (u16*)(ws + 7 * BF);               // 6 x 256x256 bf16 weights (786432 B)
  char* pb = ws + 7 * BF + 1048576;
  float* Pbuf = (float*)(pb);                   // NCH*NCHAN f32 = 4 MB
  float* qbuf = (float*)(pb + 4194304);
  float* hst  = (float*)(pb + 8388608);
  (void)ws_size; (void)in_sizes; (void)n_in; (void)out_size;

  float* outp = (float*)d_out;                  // (B,T,512)
  float* hnp  = outp + (size_t)33554432;        // (2,B,256)

  dim3 gg(512, 2, 2);

  prep_kernel<<<8384, 256, 0, stream>>>(x, xf, Wf_in, Uf_z, Wf_rec, Wb_in, Ub_z, Wb_rec, wbf);

  // z = tanh(x W_in^T + b_in); z==1 reads x time-reversed per batch
  gemm_k<0, 1><<<gg, 256, 0, stream>>>(xf, 0, wbf + 0 * 65536, bf_in, bb_in, nullptr, z0);
  // zu = z U_z^T + b_u
  gemm_k<1, 0><<<gg, 256, 0, stream>>>(z0, MH, wbf + 1 * 65536, bf_u, bb_u, nullptr, zu0);

  // DEER iteration 1 (h_prev = 0): 3-pass chunked scan -> s1 (shifted states)
  scan_p1_kernel<1><<<1024, 256, 0, stream>>>(z0, zu0, s10, Wf_rec, Wb_rec, Pbuf, qbuf);
  scan_p2_kernel<<<16, 256, 0, stream>>>(Pbuf, qbuf, hst);
  scan_p3_kernel<1><<<1024, 256, 0, stream>>>(z0, zu0, s10, Wf_rec, Wb_rec, hst,
                                              s10, nullptr, nullptr);

  // zuh = zu + states1_shifted W_rec^T  (in-place into zu)
  gemm_k<3, 0><<<gg, 256, 0, stream>>>(s10, MH, wbf + 2 * 65536, nullptr, nullptr, zu0, zu0);

  // DEER iteration 2: 3-pass chunked scan -> output + h_n
  scan_p1_kernel<2><<<1024, 256, 0, stream>>>(z0, zu0, s10, Wf_rec, Wb_rec, Pbuf, qbuf);
  scan_p2_kernel<<<16, 256, 0, stream>>>(Pbuf, qbuf, hst);
  scan_p3_kernel<2><<<1024, 256, 0, stream>>>(z0, zu0, s10, Wf_rec, Wb_rec, hst,
                                              nullptr, outp, hnp);
}

// Round 5
// 330.469 us; speedup vs baseline: 4.3121x; 1.1281x over previous
//
#include <hip/hip_runtime.h>
#include <stdint.h>

typedef unsigned short u16;
typedef __attribute__((ext_vector_type(8))) short short8v;
typedef __attribute__((ext_vector_type(4))) short short4v;
typedef __attribute__((ext_vector_type(4))) float f32x4;

#define B_ 8
#define T_ 8192
#define H_ 256
#define M_ 65536            // B_*T_
#define MH 16777216         // M_*H_
#define NCH 256             // chunks along T
#define CHL 32              // T_/NCH
#define NCHAN 4096          // 2*B_*H_

__device__ __forceinline__ u16 f2bf(float f) {
  union { float f; uint32_t u; } v; v.f = f;
  return (u16)((v.u + 0x7FFFu + ((v.u >> 16) & 1u)) >> 16);
}
__device__ __forceinline__ float bf2f(u16 s) {
  union { uint32_t u; float f; } v; v.u = ((uint32_t)s) << 16;
  return v.f;
}
__device__ __forceinline__ float sigm(float x) {
  return __fdividef(1.0f, 1.0f + __expf(-x));
}
__device__ __forceinline__ float tanhfast(float x) {
  return 1.0f - __fdividef(2.0f, __expf(2.0f * x) + 1.0f);
}

// A_t, b_t of the linearized recurrence. A at t=0 is irrelevant downstream
// (h_{-1}=0 zeroes its contribution in P/q/h), so no special-casing.
__device__ __forceinline__ void compute_Ab(float zf, float ag, float hp, float dr,
                                           float& Aa, float& bb) {
  const float u = sigm(ag);
  const float g = u * (1.f - u) * dr;
  Aa = u + (hp - zf) * g;
  bb = u * hp + (1.f - u) * zf - Aa * hp;
}

// ---------------- prep: cvt x -> bf16, cvt weights -> bf16 ----------------
__global__ __launch_bounds__(256) void prep_kernel(
    const float* __restrict__ x, u16* __restrict__ xf,
    const float* __restrict__ w0, const float* __restrict__ w1, const float* __restrict__ w2,
    const float* __restrict__ w3, const float* __restrict__ w4, const float* __restrict__ w5,
    u16* __restrict__ wbf) {
  const int bx = blockIdx.x;
  const float* src;
  u16* dst;
  size_t i;
  if (bx < 8192) {
    i = ((size_t)bx * 256 + threadIdx.x) * 8;
    src = x; dst = xf;
  } else {
    const int r = bx - 8192;
    const int wsel = r >> 5, blk = r & 31;
    src = (wsel == 0) ? w0 : (wsel == 1) ? w1 : (wsel == 2) ? w2
        : (wsel == 3) ? w3 : (wsel == 4) ? w4 : w5;
    dst = wbf + (size_t)wsel * 65536;
    i = ((size_t)blk * 256 + threadIdx.x) * 8;
  }
  const float4* s4 = (const float4*)(src + i);
  float4 a = s4[0], b = s4[1];
  short8v o;
  o[0] = (short)f2bf(a.x); o[1] = (short)f2bf(a.y);
  o[2] = (short)f2bf(a.z); o[3] = (short)f2bf(a.w);
  o[4] = (short)f2bf(b.x); o[5] = (short)f2bf(b.y);
  o[6] = (short)f2bf(b.z); o[7] = (short)f2bf(b.w);
  *(short8v*)(dst + i) = o;
}

// ---------------- GEMM: C[m,n] = epi(sum_k A[m,k]*Bw[n,k]) ----------------
// A: M x 256 bf16 row-major; Bw: 256x256 bf16 (N,K); C: M x 256 bf16.
// blockIdx.z selects direction: A += z*strideA, Bw += z*196608, C/addm/zp += z*MH.
// EPI: 0 = tanh(+bias), 1 = +bias, 3 = +addm (in-place OK).
// REVZ: if set, z==1 reads A rows time-reversed per batch.
// FUSE: 0 none; 1 = scan pass-1 iter1 (zf = A tile rows, ag = C tile);
//       2 = scan pass-1 iter2 (hp = A tile rows = s1, zf = zp_g, ag = C tile = zuh).
// A 128-row tile = 4 chunks (CHL=32) x 128 h-cols; P,q written per (chunk, channel).
__device__ __forceinline__ void g2l16(const void* g, void* l) {
  __builtin_amdgcn_global_load_lds((const __attribute__((address_space(1))) void*)g,
                                   (__attribute__((address_space(3))) void*)l, 16, 0, 0);
}

template <int EPI, int REVZ, int FUSE>
__global__ __launch_bounds__(256) void gemm_k(const u16* __restrict__ A, size_t strideA,
                                              const u16* __restrict__ Bw,
                                              const float* __restrict__ bias0,
                                              const float* __restrict__ bias1,
                                              const u16* addm, u16* C,
                                              const u16* zp_g,
                                              const float* __restrict__ Wf_rec,
                                              const float* __restrict__ Wb_rec,
                                              float* __restrict__ Pout,
                                              float* __restrict__ qout) {
  __shared__ __align__(16) char lds[32768];
  char* ldsA = lds;
  char* ldsB = lds + 16384;
  const int bz = blockIdx.z;
  A += (size_t)bz * strideA;
  Bw += (size_t)bz * 196608;
  C += (size_t)bz * (size_t)MH;
  if (EPI == 3) addm += (size_t)bz * (size_t)MH;
  if (FUSE == 2) zp_g += (size_t)bz * (size_t)MH;
  const float* bias = bz ? bias1 : bias0;

  const int tid = threadIdx.x;
  const int l = tid & 63, w = tid >> 6;
  const int tm = blockIdx.x, tn = blockIdx.y;
  const int m0 = (w >> 1) * 64, n0 = (w & 1) * 64;
  const int wbase = w * 1024;
  const bool rev = REVZ && (bz == 1);

  f32x4 vzero = {0.f, 0.f, 0.f, 0.f};
  f32x4 acc[4][4];
#pragma unroll
  for (int i = 0; i < 4; ++i)
#pragma unroll
    for (int j = 0; j < 4; ++j) acc[i][j] = vzero;

#pragma unroll
  for (int k0 = 0; k0 < 256; k0 += 64) {
#pragma unroll
    for (int is = 0; is < 4; ++is) {
      const int o = is * 4096 + tid * 16;
      const int row = o >> 7;                   // 0..127
      const int cb = o & 127;                   // byte within 128B row
      int rA = tm * 128 + row;
      if (rev) { int bb = rA >> 13; int t = rA & 8191; rA = (bb << 13) + (8191 - t); }
      const char* gA = (const char*)A + (size_t)rA * 512 + k0 * 2 + cb;
      g2l16(gA, ldsA + is * 4096 + wbase);
      const int rB = tn * 128 + row;
      const char* gB = (const char*)Bw + (size_t)rB * 512 + k0 * 2 + cb;
      g2l16(gB, ldsB + is * 4096 + wbase);
    }
    __syncthreads();                            // drains vmcnt (global_load_lds) + barrier
#pragma unroll
    for (int ks = 0; ks < 2; ++ks) {
      short8v av[4], bv[4];
#pragma unroll
      for (int i = 0; i < 4; ++i) {
        av[i] = *(const short8v*)(ldsA + (m0 + i * 16 + (l & 15)) * 128 + ks * 64 + (l >> 4) * 16);
        bv[i] = *(const short8v*)(ldsB + (n0 + i * 16 + (l & 15)) * 128 + ks * 64 + (l >> 4) * 16);
      }
#pragma unroll
      for (int i = 0; i < 4; ++i)
#pragma unroll
        for (int j = 0; j < 4; ++j)
          acc[i][j] = __builtin_amdgcn_mfma_f32_16x16x32_bf16(av[i], bv[j], acc[i][j], 0, 0, 0);
    }
    __syncthreads();                            // protect LDS before next stage
  }

  // epilogue: D col = lane&15, row = (lane>>4)*4 + r  -> stage bf16 tile in LDS,
  // then coalesced short8 stores.
  u16* lt = (u16*)lds;
  const int colL = n0 + (l & 15);
  const int rowL0 = m0 + ((l >> 4) << 2);
#pragma unroll
  for (int j = 0; j < 4; ++j) {
    const int cl = colL + j * 16;
    const int cg = tn * 128 + cl;
    const float bv = (EPI == 3) ? 0.f : bias[cg];
#pragma unroll
    for (int i = 0; i < 4; ++i)
#pragma unroll
      for (int r = 0; r < 4; ++r) {
        const int rl = rowL0 + i * 16 + r;
        float xv = acc[i][j][r] + bv;
        if (EPI == 3) xv += bf2f(addm[(size_t)(tm * 128 + rl) * 256 + cg]);
        if (EPI == 0) xv = tanhfast(xv);
        lt[rl * 128 + cl] = f2bf(xv);
      }
  }
  __syncthreads();
#pragma unroll
  for (int itr = 0; itr < 8; ++itr) {
    const int rl = w * 32 + itr * 4 + (l >> 4);
    const int cb = (l & 15) * 16;               // byte offset in 256B tile row
    short8v v = *(const short8v*)((const char*)lt + rl * 256 + cb);
    *(short8v*)((char*)C + (size_t)(tm * 128 + rl) * 512 + tn * 256 + cb) = v;
  }

  // ---- fused scan pass-1 over this tile (4 chunks x 128 h) ----
  if (FUSE) {
    const int cl = tid & 127;                   // h within tile
    const int hg = tn * 128 + cl;               // global h
    const float dr = (bz ? Wb_rec : Wf_rec)[hg * 257];
    const int bb = (tm * 128) >> 13;            // batch
    const int c0 = ((tm * 128) & 8191) >> 5;    // first chunk of tile
    const int ch = (bz * 8 + bb) * 256 + hg;
#pragma unroll
    for (int cc = 0; cc < 2; ++cc) {
      const int clc = (tid >> 7) * 2 + cc;      // local chunk 0..3
      float Pv = 1.f, qv = 0.f;
      const size_t gbase = (size_t)(tm * 128 + clc * CHL) * 256 + hg;
#pragma unroll 4
      for (int it = 0; it < CHL; ++it) {
        const float ag = bf2f(lt[(clc * CHL + it) * 128 + cl]);
        float zf, hp;
        if (FUSE == 1) { zf = bf2f(A[gbase + (size_t)it * 256]); hp = 0.f; }
        else { zf = bf2f(zp_g[gbase + (size_t)it * 256]); hp = bf2f(A[gbase + (size_t)it * 256]); }
        float Aa, bbv;
        compute_Ab(zf, ag, hp, dr, Aa, bbv);
        qv = Aa * qv + bbv;
        Pv *= Aa;
      }
      Pout[(size_t)(c0 + clc) * NCHAN + ch] = Pv;
      qout[(size_t)(c0 + clc) * NCHAN + ch] = qv;
    }
  }
}

// ---------------- scan pass 2: exclusive scan over chunk summaries ----------------
__global__ __launch_bounds__(256) void scan_p2_kernel(const float* __restrict__ P,
                                                      const float* __restrict__ q,
                                                      float* __restrict__ hstart) {
  const int ch = blockIdx.x * 256 + threadIdx.x;    // 0..4095
  float hs = 0.f;
#pragma unroll 8
  for (int c = 0; c < NCH; ++c) {
    hstart[c * NCHAN + ch] = hs;
    hs = P[c * NCHAN + ch] * hs + q[c * NCHAN + ch];
  }
}

// ---------------- scan pass 3: replay chunk with known h_start ----------------
template <int ITER>
__global__ __launch_bounds__(256) void scan_p3_kernel(
    const u16* __restrict__ zb, const u16* __restrict__ zub,
    const u16* __restrict__ s1b,
    const float* __restrict__ Wf_rec, const float* __restrict__ Wb_rec,
    const float* __restrict__ hstart,
    u16* __restrict__ s1out, float* __restrict__ out, float* __restrict__ hn) {
  const int wid = blockIdx.x * 4 + (threadIdx.x >> 6);
  const int lane = threadIdx.x & 63;
  const int c = wid & (NCH - 1);
  const int tmp = wid >> 8;
  const int b = tmp & 7;
  const int d = tmp >> 3;
  const int h0 = lane * 4;
  const float* Wr = d ? Wb_rec : Wf_rec;
  float dr[4];
#pragma unroll
  for (int j = 0; j < 4; ++j) dr[j] = Wr[(h0 + j) * 257];
  const size_t off = (size_t)d * MH + ((size_t)b * T_ + (size_t)c * CHL) * H_ + h0;
  const u16* zp = zb + off;
  const u16* zup = zub + off;
  const u16* s1p = s1b + off;
  const int ch0 = (d * 8 + b) * 256 + h0;
  f32x4 h4 = *(const f32x4*)(hstart + (size_t)c * NCHAN + ch0);
  float hc[4] = {h4[0], h4[1], h4[2], h4[3]};
  if (ITER == 1 && c == 0) {
    // s1 holds states1 shifted by +1 row; row t=0 is h_{-1} = 0
    *(short4v*)(s1out + off) = (short4v){0, 0, 0, 0};
  }
#pragma unroll 4
  for (int it = 0; it < CHL; ++it) {
    const size_t ix = (size_t)it * H_;
    short4v z4 = *(const short4v*)(zp + ix);
    short4v a4 = *(const short4v*)(zup + ix);
    short4v s4 = {0, 0, 0, 0};
    if (ITER == 2) s4 = *(const short4v*)(s1p + ix);
#pragma unroll
    for (int j = 0; j < 4; ++j) {
      const float zf = bf2f((u16)z4[j]);
      const float ag = bf2f((u16)a4[j]);
      const float hp = (ITER == 2) ? bf2f((u16)s4[j]) : 0.f;
      float Aa, bb;
      compute_Ab(zf, ag, hp, dr[j], Aa, bb);
      hc[j] = Aa * hc[j] + bb;
    }
    const int t = c * CHL + it;
    if (ITER == 1) {
      if (t < T_ - 1) {
        short4v o = {(short)f2bf(hc[0]), (short)f2bf(hc[1]),
                     (short)f2bf(hc[2]), (short)f2bf(hc[3])};
        *(short4v*)(s1out + off + ix + H_) = o;   // row t+1
      }
    } else {
      const size_t to = (d == 0) ? ((size_t)b * T_ + t) * 512 + h0
                                 : ((size_t)b * T_ + (T_ - 1 - t)) * 512 + 256 + h0;
      *(f32x4*)(out + to) = (f32x4){hc[0], hc[1], hc[2], hc[3]};
      if (t == T_ - 1)
        *(f32x4*)(hn + (size_t)(d * 8 + b) * 256 + h0) = (f32x4){hc[0], hc[1], hc[2], hc[3]};
    }
  }
}

// ---------------- host ----------------
extern "C" void kernel_launch(void* const* d_in, const int* in_sizes, int n_in,
                              void* d_out, int out_size, void* d_ws, size_t ws_size,
                              hipStream_t stream) {
  const float* x      = (const float*)d_in[0];
  const float* Wf_in  = (const float*)d_in[1];
  const float* bf_in  = (const float*)d_in[2];
  const float* Wf_rec = (const float*)d_in[3];
  const float* Uf_z   = (const float*)d_in[4];
  const float* bf_u   = (const float*)d_in[5];
  const float* Wb_in  = (const float*)d_in[6];
  const float* bb_in  = (const float*)d_in[7];
  const float* Wb_rec = (const float*)d_in[8];
  const float* Ub_z   = (const float*)d_in[9];
  const float* bb_u   = (const float*)d_in[10];

  char* ws = (char*)d_ws;
  const size_t BF = 33554432;                   // bytes of one bf16 [M_ x H_] buffer
  u16* xf  = (u16*)(ws + 0 * BF);               // x as bf16
  u16* z0  = (u16*)(ws + 1 * BF);               // z, dirs contiguous [2][M][H]
  u16* zu0 = (u16*)(ws + 3 * BF);               // zu, then zuh = zu + s1*W (in-place)
  u16* s10 = (u16*)(ws + 5 * BF);               // states1 shifted (+1 row), dirs contiguous
  u16* wbf = (u16*)(ws + 7 * BF);               // 6 x 256x256 bf16 weights (786432 B)
  char* pb = ws + 7 * BF + 1048576;
  float* Pbuf = (float*)(pb);                   // NCH*NCHAN f32 = 4 MB
  float* qbuf = (float*)(pb + 4194304);
  float* hst  = (float*)(pb + 8388608);
  (void)ws_size; (void)in_sizes; (void)n_in; (void)out_size;

  float* outp = (float*)d_out;                  // (B,T,512)
  float* hnp  = outp + (size_t)33554432;        // (2,B,256)

  dim3 gg(512, 2, 2);

  prep_kernel<<<8384, 256, 0, stream>>>(x, xf, Wf_in, Uf_z, Wf_rec, Wb_in, Ub_z, Wb_rec, wbf);

  // z = tanh(x W_in^T + b_in); z==1 reads x time-reversed per batch
  gemm_k<0, 1, 0><<<gg, 256, 0, stream>>>(xf, 0, wbf + 0 * 65536, bf_in, bb_in,
                                          nullptr, z0, nullptr, nullptr, nullptr,
                                          nullptr, nullptr);
  // zu = z U_z^T + b_u, fused scan-p1 (iter 1)
  gemm_k<1, 0, 1><<<gg, 256, 0, stream>>>(z0, MH, wbf + 1 * 65536, bf_u, bb_u,
                                          nullptr, zu0, nullptr, Wf_rec, Wb_rec,
                                          Pbuf, qbuf);

  // DEER iteration 1 (h_prev = 0): p2 then replay -> s1 (shifted states)
  scan_p2_kernel<<<16, 256, 0, stream>>>(Pbuf, qbuf, hst);
  scan_p3_kernel<1><<<1024, 256, 0, stream>>>(z0, zu0, s10, Wf_rec, Wb_rec, hst,
                                              s10, nullptr, nullptr);

  // zuh = zu + states1_shifted W_rec^T (in-place into zu), fused scan-p1 (iter 2)
  gemm_k<3, 0, 2><<<gg, 256, 0, stream>>>(s10, MH, wbf + 2 * 65536, nullptr, nullptr,
                                          zu0, zu0, z0, Wf_rec, Wb_rec,
                                          Pbuf, qbuf);

  // DEER iteration 2: p2 then replay -> output + h_n
  scan_p2_kernel<<<16, 256, 0, stream>>>(Pbuf, qbuf, hst);
  scan_p3_kernel<2><<<1024, 256, 0, stream>>>(z0, zu0, s10, Wf_rec, Wb_rec, hst,
                                              nullptr, outp, hnp);
}